// Round 2
// baseline (652.428 us; speedup 1.0000x reference)
//
#include <hip/hip_runtime.h>
#include <cstdint>

#define AS1 __attribute__((address_space(1)))
#define AS3 __attribute__((address_space(3)))

typedef __bf16 v8bf __attribute__((ext_vector_type(8)));
typedef float  v4f  __attribute__((ext_vector_type(4)));

__device__ __forceinline__ uint32_t f2u(float f) {
    union { float f; uint32_t u; } v; v.f = f; return v.u;
}
__device__ __forceinline__ uint16_t f2bf_rne(float f) {   // finite inputs
    uint32_t u = f2u(f);
    return (uint16_t)((u + 0x7FFFu + ((u >> 16) & 1u)) >> 16);
}
__device__ __forceinline__ uint32_t pack2(float a, float b) {
    return (uint32_t)f2bf_rne(a) | ((uint32_t)f2bf_rne(b) << 16);
}
// async global->LDS, 16B/lane; LDS dst = wave-uniform base (+lane*16 by HW)
__device__ __forceinline__ void async16(const void* g, void* l) {
    __builtin_amdgcn_global_load_lds((AS1 const void*)g, (AS3 void*)l, 16, 0, 0);
}

// ---------- prep: A_all[h][n][d] = bf16(z0[n][d]*W[h][d]); B_bf = bf16(z1) ----------
// blocks [0,16384): A_all (33.5M elems, 8/thread). blocks [16384,16512): z1 (262144 elems).
__global__ __launch_bounds__(256)
void prep_kernel(const float* __restrict__ z0, const float* __restrict__ z1,
                 const float* __restrict__ W,
                 uint16_t* __restrict__ Aall, uint16_t* __restrict__ Bbf)
{
    const int b = blockIdx.x;
    if (b < 16384) {
        const size_t e0 = ((size_t)b * 256 + threadIdx.x) * 8;
        const int h  = (int)(e0 >> 18);           // N*D = 2^18
        const int nd = (int)(e0 & 0x3FFFFu);
        const int d0 = (int)(e0 & 255u);
        float4 za = *(const float4*)(z0 + nd);
        float4 zb = *(const float4*)(z0 + nd + 4);
        float4 wa = *(const float4*)(W + h * 256 + d0);
        float4 wb = *(const float4*)(W + h * 256 + d0 + 4);
        uint4 r;
        r.x = pack2(za.x * wa.x, za.y * wa.y);
        r.y = pack2(za.z * wa.z, za.w * wa.w);
        r.z = pack2(zb.x * wb.x, zb.y * wb.y);
        r.w = pack2(zb.z * wb.z, zb.w * wb.w);
        *(uint4*)(Aall + e0) = r;
    } else {
        const size_t e0 = ((size_t)(b - 16384) * 256 + threadIdx.x) * 8;
        float4 za = *(const float4*)(z1 + e0);
        float4 zb = *(const float4*)(z1 + e0 + 4);
        uint4 r;
        r.x = pack2(za.x, za.y);
        r.y = pack2(za.z, za.w);
        r.z = pack2(zb.x, zb.y);
        r.w = pack2(zb.z, zb.w);
        *(uint4*)(Bbf + e0) = r;
    }
}

// ---------- GEMM: out[h][n][m] = leaky(sum_d Aall[h][n][d]*Bbf[m][d] + bias[h]) ----------
// grid (8,8,128) = (m-tiles, n-tiles, h); block 256 = 4 waves; tile 128x128, BK=32, 8 K-steps.
// Operand roles: MFMA A-op <- z1 tile (m rows), B-op <- z0W tile (n rows) so the 4 acc regs
// per lane are 4 consecutive m -> float4 coalesced epilogue stores.
__global__ __launch_bounds__(256)
void gemm_kernel(const uint16_t* __restrict__ Aall, const uint16_t* __restrict__ Bbf,
                 const float* __restrict__ bias, float* __restrict__ out)
{
    __shared__ __align__(16) uint16_t aT[128 * 32];   // z0W rows [n][k], stride 32
    __shared__ __align__(16) uint16_t bT[128 * 32];   // z1  rows [m][k], stride 32

    const int t = threadIdx.x, wave = t >> 6, lane = t & 63;
    const int h = blockIdx.z, n0 = blockIdx.y * 128, m0 = blockIdx.x * 128;
    const uint16_t* Ab = Aall + ((size_t)h << 18) + ((size_t)n0 << 8);
    const uint16_t* Bb = Bbf + ((size_t)m0 << 8);

    const int rowA = t >> 2;        // 0..63
    const int col8 = (t & 3) * 8;

    v4f acc[4][4];
#pragma unroll
    for (int r = 0; r < 4; ++r)
#pragma unroll
        for (int c = 0; c < 4; ++c) acc[r][c] = (v4f){0.f, 0.f, 0.f, 0.f};

    const int mbw = (wave & 1) * 64;   // wave's m sub-block (A-operand side)
    const int nb  = (wave >> 1) * 64;  // wave's n sub-block (B-operand side)
    const int fr  = lane & 15;
    const int kq  = (lane >> 4) * 8;

    for (int ks = 0; ks < 8; ++ks) {
        const int k0 = ks * 32;
        async16(Ab + (size_t)rowA * 256 + k0 + col8,        &aT[(wave * 64) * 8]);
        async16(Ab + (size_t)(rowA + 64) * 256 + k0 + col8, &aT[(256 + wave * 64) * 8]);
        async16(Bb + (size_t)rowA * 256 + k0 + col8,        &bT[(wave * 64) * 8]);
        async16(Bb + (size_t)(rowA + 64) * 256 + k0 + col8, &bT[(256 + wave * 64) * 8]);
        __syncthreads();

        v8bf am[4], bn[4];
#pragma unroll
        for (int r = 0; r < 4; ++r)
            am[r] = *(const v8bf*)&bT[(mbw + r * 16 + fr) * 32 + kq];
#pragma unroll
        for (int c = 0; c < 4; ++c)
            bn[c] = *(const v8bf*)&aT[(nb + c * 16 + fr) * 32 + kq];
#pragma unroll
        for (int r = 0; r < 4; ++r)
#pragma unroll
            for (int c = 0; c < 4; ++c)
                acc[r][c] = __builtin_amdgcn_mfma_f32_16x16x32_bf16(am[r], bn[c], acc[r][c], 0, 0, 0);

        __syncthreads();
    }

    // epilogue: D[row=m][col=n]; row = (lane>>4)*4 + reg, col = lane&15 (m89/m97-verified layout)
    const float bsf = bias[h];
    float* outB = out + ((size_t)h << 20) + ((size_t)n0 << 10) + m0;
    const int mq = (lane >> 4) * 4;
#pragma unroll
    for (int r = 0; r < 4; ++r) {
#pragma unroll
        for (int c = 0; c < 4; ++c) {
            const int n = nb + c * 16 + fr;
            const int m = mbw + r * 16 + mq;
            float4 o;
            float v0 = acc[r][c][0] + bsf; o.x = (v0 >= 0.f) ? v0 : 0.2f * v0;
            float v1 = acc[r][c][1] + bsf; o.y = (v1 >= 0.f) ? v1 : 0.2f * v1;
            float v2 = acc[r][c][2] + bsf; o.z = (v2 >= 0.f) ? v2 : 0.2f * v2;
            float v3 = acc[r][c][3] + bsf; o.w = (v3 >= 0.f) ? v3 : 0.2f * v3;
            *(float4*)(outB + ((size_t)n << 10) + m) = o;
        }
    }
}

// ---------- fallback: same GEMM but converts f32->bf16 in-kernel (no workspace) ----------
__global__ __launch_bounds__(256)
void gemm_fb(const float* __restrict__ z0, const float* __restrict__ z1,
             const float* __restrict__ W, const float* __restrict__ bias,
             float* __restrict__ out)
{
    __shared__ __align__(16) uint16_t aT[128 * 32];
    __shared__ __align__(16) uint16_t bT[128 * 32];
    const int t = threadIdx.x, wave = t >> 6, lane = t & 63;
    const int h = blockIdx.z, n0 = blockIdx.y * 128, m0 = blockIdx.x * 128;
    const float* Ab = z0 + (size_t)n0 * 256;
    const float* Bb = z1 + (size_t)m0 * 256;
    const int rowA = t >> 2, col8 = (t & 3) * 8;

    v4f acc[4][4];
#pragma unroll
    for (int r = 0; r < 4; ++r)
#pragma unroll
        for (int c = 0; c < 4; ++c) acc[r][c] = (v4f){0.f, 0.f, 0.f, 0.f};

    const int mbw = (wave & 1) * 64, nb = (wave >> 1) * 64;
    const int fr = lane & 15, kq = (lane >> 4) * 8;

    for (int ks = 0; ks < 8; ++ks) {
        const int k0 = ks * 32;
        float4 wa = *(const float4*)(W + h * 256 + k0 + col8);
        float4 wb = *(const float4*)(W + h * 256 + k0 + col8 + 4);
#pragma unroll
        for (int i = 0; i < 2; ++i) {
            const int row = i * 64 + rowA;
            float4 za = *(const float4*)(Ab + (size_t)row * 256 + k0 + col8);
            float4 zb = *(const float4*)(Ab + (size_t)row * 256 + k0 + col8 + 4);
            uint4 r;
            r.x = pack2(za.x * wa.x, za.y * wa.y);
            r.y = pack2(za.z * wa.z, za.w * wa.w);
            r.z = pack2(zb.x * wb.x, zb.y * wb.y);
            r.w = pack2(zb.z * wb.z, zb.w * wb.w);
            *(uint4*)&aT[(i * 256 + t) * 8] = r;
            float4 ba = *(const float4*)(Bb + (size_t)row * 256 + k0 + col8);
            float4 bb = *(const float4*)(Bb + (size_t)row * 256 + k0 + col8 + 4);
            uint4 s;
            s.x = pack2(ba.x, ba.y);
            s.y = pack2(ba.z, ba.w);
            s.z = pack2(bb.x, bb.y);
            s.w = pack2(bb.z, bb.w);
            *(uint4*)&bT[(i * 256 + t) * 8] = s;
        }
        __syncthreads();

        v8bf am[4], bn[4];
#pragma unroll
        for (int r = 0; r < 4; ++r)
            am[r] = *(const v8bf*)&bT[(mbw + r * 16 + fr) * 32 + kq];
#pragma unroll
        for (int c = 0; c < 4; ++c)
            bn[c] = *(const v8bf*)&aT[(nb + c * 16 + fr) * 32 + kq];
#pragma unroll
        for (int r = 0; r < 4; ++r)
#pragma unroll
            for (int c = 0; c < 4; ++c)
                acc[r][c] = __builtin_amdgcn_mfma_f32_16x16x32_bf16(am[r], bn[c], acc[r][c], 0, 0, 0);
        __syncthreads();
    }

    const float bsf = bias[h];
    float* outB = out + ((size_t)h << 20) + ((size_t)n0 << 10) + m0;
    const int mq = (lane >> 4) * 4;
#pragma unroll
    for (int r = 0; r < 4; ++r) {
#pragma unroll
        for (int c = 0; c < 4; ++c) {
            const int n = nb + c * 16 + fr;
            const int m = mbw + r * 16 + mq;
            float4 o;
            float v0 = acc[r][c][0] + bsf; o.x = (v0 >= 0.f) ? v0 : 0.2f * v0;
            float v1 = acc[r][c][1] + bsf; o.y = (v1 >= 0.f) ? v1 : 0.2f * v1;
            float v2 = acc[r][c][2] + bsf; o.z = (v2 >= 0.f) ? v2 : 0.2f * v2;
            float v3 = acc[r][c][3] + bsf; o.w = (v3 >= 0.f) ? v3 : 0.2f * v3;
            *(float4*)(outB + ((size_t)n << 10) + m) = o;
        }
    }
}

extern "C" void kernel_launch(void* const* d_in, const int* in_sizes, int n_in,
                              void* d_out, int out_size, void* d_ws, size_t ws_size,
                              hipStream_t stream) {
    (void)in_sizes; (void)n_in; (void)out_size;
    const float* z0   = (const float*)d_in[0];
    const float* z1   = (const float*)d_in[1];
    const float* Wm   = (const float*)d_in[2];
    const float* bias = (const float*)d_in[3];
    float* out = (float*)d_out;

    const size_t aall_bytes = (size_t)128 * 1024 * 256 * 2;           // 64 MiB
    const size_t need = aall_bytes + (size_t)1024 * 256 * 2;          // + 512 KiB
    dim3 grid(8, 8, 128), block(256);
    if (ws_size >= need) {
        uint16_t* Aall = (uint16_t*)d_ws;
        uint16_t* Bbf  = (uint16_t*)((char*)d_ws + aall_bytes);
        prep_kernel<<<16512, 256, 0, stream>>>(z0, z1, Wm, Aall, Bbf);
        gemm_kernel<<<grid, block, 0, stream>>>(Aall, Bbf, bias, out);
    } else {
        gemm_fb<<<grid, block, 0, stream>>>(z0, z1, Wm, bias, out);
    }
}